// Round 4
// baseline (221.831 us; speedup 1.0000x reference)
//
#include <hip/hip_runtime.h>

#define ALPHA 0.2f

__device__ __forceinline__ float dot4(float4 a, float4 b) {
    return a.x * b.x + a.y * b.y + a.z * b.z + a.w * b.w;
}

__device__ __forceinline__ void wave_lds_fence() {
    asm volatile("s_waitcnt lgkmcnt(0)" ::: "memory");
    __builtin_amdgcn_sched_barrier(0);
}

// K1: one wave per node (grid-stride), full-node register prefetch,
// rel*ent products staged in a per-wave LDS slab. No block barriers.
__global__ __launch_bounds__(256, 2)
void gat_k1(const float* __restrict__ item,
            const float* __restrict__ ent,
            const float* __restrict__ rel,
            const int*   __restrict__ rel_ids,
            const int*   __restrict__ adj,
            const float* __restrict__ fc_w,
            const float* __restrict__ fc_b,
            const float* __restrict__ probs,
            float* __restrict__ y,
            int N, int R, int NW)
{
    __shared__ __align__(16) float slab[4][4096];   // per-wave product slab, 64 KB
    __shared__ float strip[4][32];                  // per-wave e redistribution

    const int t  = threadIdx.x;
    const int wv = t >> 6;           // wave in block
    const int l  = t & 63;           // lane
    const int lh = l & 31;           // lane-in-half (k for softmax, d-quad for data)
    const int hi = l >> 5;           // half index (k parity for chunks)

    const float4 fi = *(const float4*)&fc_w[4 * lh];
    const float4 fr = *(const float4*)&fc_w[128 + 4 * lh];
    const float4 fe = *(const float4*)&fc_w[256 + 4 * lh];
    const float  fcb = fc_b[0];

    const int wid = blockIdx.x * 4 + wv;
    if (wid >= N) return;

    // prologue: issue node wid's 32 big loads into the register buffer
    float4 rn[16], en[16];
    {
        const float* bR = rel + (size_t)wid * 4096 + 4 * l;
        const float* bE = ent + (size_t)wid * 4096 + 4 * l;
        #pragma unroll
        for (int c = 0; c < 16; ++c) {
            rn[c] = *(const float4*)(bR + c * 256);
            en[c] = *(const float4*)(bE + c * 256);
        }
    }

    for (int n = wid; n < N; n += NW) {
        // small per-node loads (independent; overlap with big-stream waits)
        const float4 item4 = *(const float4*)&item[(size_t)n * 128 + 4 * lh];
        const int adjv = adj[(size_t)n * 32 + lh];
        const int idv  = rel_ids[(size_t)n * 32 + lh];
        const bool vld = (idv >= 0) && (idv < R);
        const float4 q = *(const float4*)&probs[(vld ? idv : 0) * 4];

        // ---- Phase 1: consume prefetched regs -> slab products + e-partials
        float ep[16];
        #pragma unroll
        for (int c = 0; c < 16; ++c) {
            float4 pp;
            pp.x = rn[c].x * en[c].x;
            pp.y = rn[c].y * en[c].y;
            pp.z = rn[c].z * en[c].z;
            pp.w = rn[c].w * en[c].w;
            *(float4*)&slab[wv][c * 256 + 4 * l] = pp;
            ep[c] = dot4(rn[c], fr) + dot4(en[c], fe);
        }

        // ---- Phase 2: issue next node's 32 loads (in flight across phases 3-5)
        if (n + NW < N) {
            const float* bR = rel + (size_t)(n + NW) * 4096 + 4 * l;
            const float* bE = ent + (size_t)(n + NW) * 4096 + 4 * l;
            #pragma unroll
            for (int c = 0; c < 16; ++c) {
                rn[c] = *(const float4*)(bR + c * 256);
                en[c] = *(const float4*)(bE + c * 256);
            }
        }
        __builtin_amdgcn_sched_barrier(0);   // pin prefetch above the chains

        // ---- Phase 3: reduce e-partials within each 32-lane half ----------
        float sit = dot4(item4, fi);
        #pragma unroll
        for (int s = 16; s >= 1; s >>= 1) sit += __shfl_xor(sit, s, 32);

        #pragma unroll
        for (int c = 0; c < 16; ++c) {
            float v = ep[c];
            #pragma unroll
            for (int s = 16; s >= 1; s >>= 1) v += __shfl_xor(v, s, 32);
            ep[c] = v;
        }
        if (lh == 0) {
            #pragma unroll
            for (int c = 0; c < 16; ++c) strip[wv][2 * c + hi] = ep[c];
        }
        wave_lds_fence();

        // ---- Phase 4: softmax (no max-sub; fp32-safe), lane-parallel k=lh --
        float e = strip[wv][lh] + sit + fcb;
        e = (e > 0.0f) ? e : ALPHA * e;                    // LeakyReLU
        float ex = (adjv > 0) ? __expf(e) : 0.0f;          // mask
        float Z = ex;
        #pragma unroll
        for (int s = 16; s >= 1; s >>= 1) Z += __shfl_xor(Z, s, 32);
        const float a  = vld ? (q.x + q.y + q.z + q.w) : 0.0f;
        const float wk = (Z > 0.0f) ? (ex * a / Z) : (a * (1.0f / 32.0f));

        // ---- Phase 5: aggregate from slab, merge halves, store -------------
        float4 acc = make_float4(0.f, 0.f, 0.f, 0.f);
        #pragma unroll
        for (int c = 0; c < 16; ++c) {
            const float wc = __shfl(wk, 2 * c + hi, 64);
            const float4 pv = *(const float4*)&slab[wv][c * 256 + 4 * l];
            acc.x = fmaf(wc, pv.x, acc.x);
            acc.y = fmaf(wc, pv.y, acc.y);
            acc.z = fmaf(wc, pv.z, acc.z);
            acc.w = fmaf(wc, pv.w, acc.w);
        }
        acc.x += __shfl_xor(acc.x, 32, 64);
        acc.y += __shfl_xor(acc.y, 32, 64);
        acc.z += __shfl_xor(acc.z, 32, 64);
        acc.w += __shfl_xor(acc.w, 32, 64);

        if (l < 32) {
            float4 o;
            o.x = acc.x + item4.x;
            o.y = acc.y + item4.y;
            o.z = acc.z + item4.z;
            o.w = acc.w + item4.w;
            *(float4*)&y[(size_t)n * 128 + 4 * lh] = o;
        }
    }
}

// K2: out = relu(y @ W^T + b), in place on d_out (unchanged from R2/R3).
__device__ __forceinline__ void block_bar() {
    asm volatile("s_waitcnt lgkmcnt(0)" ::: "memory");
    __builtin_amdgcn_s_barrier();
}

__global__ __launch_bounds__(256, 4)
void gat_k2(const float* __restrict__ out_w,
            const float* __restrict__ out_b,
            float* __restrict__ y, int N)
{
    __shared__ __align__(16) float ylds[128];
    __shared__ __align__(16) float plds[1024];   // [4 a][32 g][8 c]

    const int t = threadIdx.x;
    const int c = t & 7;
    const int g = t >> 3;

    float4 w4[16];
    #pragma unroll
    for (int a = 0; a < 4; ++a)
        #pragma unroll
        for (int i = 0; i < 4; ++i)
            w4[a * 4 + i] = *(const float4*)&out_w[(size_t)(g * 4 + a) * 128 + c * 16 + i * 4];
    const float bj = out_b[t & 127];
    const int stride = gridDim.x;

    float vcur = 0.0f;
    if (t < 128) vcur = y[(size_t)blockIdx.x * 128 + t];

    for (int n = blockIdx.x; n < N; n += stride) {
        if (t < 128) ylds[t] = vcur;
        block_bar();
        int np = n + stride; if (np >= N) np = n;
        float vn = 0.0f;
        if (t < 128) vn = y[(size_t)np * 128 + t];

        float4 yc[4];
        #pragma unroll
        for (int i = 0; i < 4; ++i) yc[i] = *(const float4*)&ylds[c * 16 + i * 4];
        #pragma unroll
        for (int a = 0; a < 4; ++a) {
            float s = 0.0f;
            #pragma unroll
            for (int i = 0; i < 4; ++i) s += dot4(w4[a * 4 + i], yc[i]);
            plds[a * 256 + g * 8 + c] = s;
        }
        block_bar();
        if (t < 128) {
            const int j = t, a2 = j & 3, g2 = j >> 2;
            const float* pp = &plds[a2 * 256 + g2 * 8];
            float4 u0 = *(const float4*)pp;
            float4 u1 = *(const float4*)(pp + 4);
            float s = u0.x + u0.y + u0.z + u0.w + u1.x + u1.y + u1.z + u1.w + bj;
            y[(size_t)n * 128 + j] = fmaxf(s, 0.0f);
        }
        vcur = vn;
    }
}

extern "C" void kernel_launch(void* const* d_in, const int* in_sizes, int n_in,
                              void* d_out, int out_size, void* d_ws, size_t ws_size,
                              hipStream_t stream) {
    const float* item    = (const float*)d_in[0];
    const float* ent     = (const float*)d_in[1];
    const float* rel     = (const float*)d_in[2];
    const int*   rel_ids = (const int*)  d_in[3];
    const int*   adj     = (const int*)  d_in[4];
    const float* fc_w    = (const float*)d_in[5];
    const float* fc_b    = (const float*)d_in[6];
    const float* out_w   = (const float*)d_in[7];
    const float* out_b   = (const float*)d_in[8];
    const float* probs   = (const float*)d_in[9];
    float* out = (float*)d_out;

    const int N = in_sizes[0] / 128;   // 20000
    const int R = in_sizes[9] / 4;     // 100

    const int blocks1 = 512;           // persistent: 2 blocks/CU, 2048 waves
    const int NW = blocks1 * 4;
    hipLaunchKernelGGL(gat_k1, dim3(blocks1), dim3(256), 0, stream,
                       item, ent, rel, rel_ids, adj, fc_w, fc_b, probs, out,
                       N, R, NW);

    int blocks2 = 2048; if (blocks2 > N) blocks2 = N;
    hipLaunchKernelGGL(gat_k2, dim3(blocks2), dim3(256), 0, stream,
                       out_w, out_b, out, N);
}

// Round 5
// 159.057 us; speedup vs baseline: 1.3947x; 1.3947x over previous
//
#include <hip/hip_runtime.h>

#define ALPHA 0.2f

__device__ __forceinline__ float dot4(float4 a, float4 b) {
    return a.x * b.x + a.y * b.y + a.z * b.z + a.w * b.w;
}

__device__ __forceinline__ void lds_fence() {
    asm volatile("s_waitcnt lgkmcnt(0)" ::: "memory");
    __builtin_amdgcn_sched_barrier(0);
}

// async HBM -> LDS, 16B per lane, zero VGPR cost. LDS dest: uniform base + 16*lane.
__device__ __forceinline__ void async16(const float* g, float* l) {
    __builtin_amdgcn_global_load_lds(
        (const __attribute__((address_space(1))) void*)g,
        (__attribute__((address_space(3))) void*)l, 16, 0, 0);
}

// K1: one wave per block, one node at a time (grid-stride persistent).
// rel/ent staged via global_load_lds into a 32KB slab; counted-vmcnt e-pass.
__global__ __launch_bounds__(64, 1)
void gat_k1(const float* __restrict__ item,
            const float* __restrict__ ent,
            const float* __restrict__ rel,
            const int*   __restrict__ rel_ids,
            const int*   __restrict__ adj,
            const float* __restrict__ fc_w,
            const float* __restrict__ fc_b,
            const float* __restrict__ probs,
            float* __restrict__ y,
            int N, int R)
{
    __shared__ __align__(16) float slab[8192];   // rel: [0,4096) | ent: [4096,8192)
    __shared__ float strip[32];
    __shared__ float asum[128];

    const int l  = threadIdx.x;      // 0..63
    const int lh = l & 31;
    const int hi = l >> 5;

    // ---- prologue: probs row-sums into LDS; fc_w fragments into regs ------
    for (int i = l; i < R; i += 64) {
        float4 q = *(const float4*)&probs[i * 4];
        asum[i] = q.x + q.y + q.z + q.w;
    }
    const float4 fi = *(const float4*)&fc_w[4 * lh];
    const float4 fr = *(const float4*)&fc_w[128 + 4 * lh];
    const float4 fe = *(const float4*)&fc_w[256 + 4 * lh];
    const float  fcb = fc_b[0];
    lds_fence();

    for (int n = blockIdx.x; n < N; n += gridDim.x) {
        // small per-node loads (oldest in the vmcnt queue)
        const float4 item4 = *(const float4*)&item[(size_t)n * 128 + 4 * lh];
        const int adjv = adj[(size_t)n * 32 + lh];
        const int idv  = rel_ids[(size_t)n * 32 + lh];

        // ---- issue 32 async loads, rel/ent interleaved per chunk ----------
        const float* bR = rel + (size_t)n * 4096 + 4 * l;
        const float* bE = ent + (size_t)n * 4096 + 4 * l;
        #pragma unroll
        for (int c = 0; c < 16; ++c) {
            async16(bR + c * 256, &slab[c * 256]);
            async16(bE + c * 256, &slab[4096 + c * 256]);
        }

        // ---- e-pass: wait only for chunk c (vmcnt counts retire in order) --
        // chunk c ready when the newest (30-2c) ops may still be pending;
        // immediates use margin 2 (covers the y-store from the previous node).
        float ep[16];
#define ECHUNK(c, imm) \
        asm volatile("s_waitcnt vmcnt(" imm ")" ::: "memory"); \
        __builtin_amdgcn_sched_barrier(0); \
        { float4 rv = *(const float4*)&slab[(c) * 256 + 4 * l]; \
          float4 ev = *(const float4*)&slab[4096 + (c) * 256 + 4 * l]; \
          ep[(c)] = dot4(rv, fr) + dot4(ev, fe); }
        ECHUNK(0, "28")  ECHUNK(1, "26")  ECHUNK(2, "24")  ECHUNK(3, "22")
        ECHUNK(4, "20")  ECHUNK(5, "18")  ECHUNK(6, "16")  ECHUNK(7, "14")
        ECHUNK(8, "12")  ECHUNK(9, "10")  ECHUNK(10, "8")  ECHUNK(11, "6")
        ECHUNK(12, "4")  ECHUNK(13, "2")  ECHUNK(14, "0")  ECHUNK(15, "0")
#undef ECHUNK

        // ---- reduce e-partials within each 32-lane half -------------------
        float sit = dot4(item4, fi);
        #pragma unroll
        for (int s = 16; s >= 1; s >>= 1) sit += __shfl_xor(sit, s, 32);

        #pragma unroll
        for (int c = 0; c < 16; ++c) {
            float v = ep[c];
            #pragma unroll
            for (int s = 16; s >= 1; s >>= 1) v += __shfl_xor(v, s, 32);
            ep[c] = v;
        }
        if (lh == 0) {
            #pragma unroll
            for (int c = 0; c < 16; ++c) strip[2 * c + hi] = ep[c];
        }
        lds_fence();

        // ---- masked softmax (no max-sub; inputs N(0,1), fp32-safe) --------
        float e = strip[lh] + sit + fcb;
        e = (e > 0.0f) ? e : ALPHA * e;                 // LeakyReLU
        float ex = (adjv > 0) ? __expf(e) : 0.0f;       // adjacency mask
        float Z = ex;
        #pragma unroll
        for (int s = 16; s >= 1; s >>= 1) Z += __shfl_xor(Z, s, 32);
        const bool  vld = (idv >= 0) && (idv < R);
        const float a   = vld ? asum[idv] : 0.0f;
        const float wk  = (Z > 0.0f) ? (ex * a / Z) : (a * (1.0f / 32.0f));

        // ---- aggregate: re-read slab, weight, merge halves, store ---------
        float4 acc = make_float4(0.f, 0.f, 0.f, 0.f);
        #pragma unroll
        for (int c = 0; c < 16; ++c) {
            const float wc = __shfl(wk, 2 * c + hi, 64);
            const float4 rv = *(const float4*)&slab[c * 256 + 4 * l];
            const float4 ev = *(const float4*)&slab[4096 + c * 256 + 4 * l];
            acc.x = fmaf(wc, rv.x * ev.x, acc.x);
            acc.y = fmaf(wc, rv.y * ev.y, acc.y);
            acc.z = fmaf(wc, rv.z * ev.z, acc.z);
            acc.w = fmaf(wc, rv.w * ev.w, acc.w);
        }
        acc.x += __shfl_xor(acc.x, 32, 64);
        acc.y += __shfl_xor(acc.y, 32, 64);
        acc.z += __shfl_xor(acc.z, 32, 64);
        acc.w += __shfl_xor(acc.w, 32, 64);

        if (l < 32) {
            float4 o;
            o.x = acc.x + item4.x;
            o.y = acc.y + item4.y;
            o.z = acc.z + item4.z;
            o.w = acc.w + item4.w;
            *(float4*)&y[(size_t)n * 128 + 4 * lh] = o;
        }
    }
}

// K2: out = relu(y @ W^T + b), in place on d_out (unchanged).
__device__ __forceinline__ void block_bar() {
    asm volatile("s_waitcnt lgkmcnt(0)" ::: "memory");
    __builtin_amdgcn_s_barrier();
}

__global__ __launch_bounds__(256, 4)
void gat_k2(const float* __restrict__ out_w,
            const float* __restrict__ out_b,
            float* __restrict__ y, int N)
{
    __shared__ __align__(16) float ylds[128];
    __shared__ __align__(16) float plds[1024];   // [4 a][32 g][8 c]

    const int t = threadIdx.x;
    const int c = t & 7;
    const int g = t >> 3;

    float4 w4[16];
    #pragma unroll
    for (int a = 0; a < 4; ++a)
        #pragma unroll
        for (int i = 0; i < 4; ++i)
            w4[a * 4 + i] = *(const float4*)&out_w[(size_t)(g * 4 + a) * 128 + c * 16 + i * 4];
    const float bj = out_b[t & 127];
    const int stride = gridDim.x;

    float vcur = 0.0f;
    if (t < 128) vcur = y[(size_t)blockIdx.x * 128 + t];

    for (int n = blockIdx.x; n < N; n += stride) {
        if (t < 128) ylds[t] = vcur;
        block_bar();
        int np = n + stride; if (np >= N) np = n;
        float vn = 0.0f;
        if (t < 128) vn = y[(size_t)np * 128 + t];

        float4 yc[4];
        #pragma unroll
        for (int i = 0; i < 4; ++i) yc[i] = *(const float4*)&ylds[c * 16 + i * 4];
        #pragma unroll
        for (int a = 0; a < 4; ++a) {
            float s = 0.0f;
            #pragma unroll
            for (int i = 0; i < 4; ++i) s += dot4(w4[a * 4 + i], yc[i]);
            plds[a * 256 + g * 8 + c] = s;
        }
        block_bar();
        if (t < 128) {
            const int j = t, a2 = j & 3, g2 = j >> 2;
            const float* pp = &plds[a2 * 256 + g2 * 8];
            float4 u0 = *(const float4*)pp;
            float4 u1 = *(const float4*)(pp + 4);
            float s = u0.x + u0.y + u0.z + u0.w + u1.x + u1.y + u1.z + u1.w + bj;
            y[(size_t)n * 128 + j] = fmaxf(s, 0.0f);
        }
        vcur = vn;
    }
}

extern "C" void kernel_launch(void* const* d_in, const int* in_sizes, int n_in,
                              void* d_out, int out_size, void* d_ws, size_t ws_size,
                              hipStream_t stream) {
    const float* item    = (const float*)d_in[0];
    const float* ent     = (const float*)d_in[1];
    const float* rel     = (const float*)d_in[2];
    const int*   rel_ids = (const int*)  d_in[3];
    const int*   adj     = (const int*)  d_in[4];
    const float* fc_w    = (const float*)d_in[5];
    const float* fc_b    = (const float*)d_in[6];
    const float* out_w   = (const float*)d_in[7];
    const float* out_b   = (const float*)d_in[8];
    const float* probs   = (const float*)d_in[9];
    float* out = (float*)d_out;

    const int N = in_sizes[0] / 128;   // 20000
    const int R = in_sizes[9] / 4;     // 100

    // 1024 persistent single-wave blocks: 4/CU (LDS-limited), no barriers.
    hipLaunchKernelGGL(gat_k1, dim3(1024), dim3(64), 0, stream,
                       item, ent, rel, rel_ids, adj, fc_w, fc_b, probs, out, N, R);

    int blocks2 = 2048; if (blocks2 > N) blocks2 = N;
    hipLaunchKernelGGL(gat_k2, dim3(blocks2), dim3(256), 0, stream,
                       out_w, out_b, out, N);
}